// Round 2
// baseline (274.388 us; speedup 1.0000x reference)
//
#include <hip/hip_runtime.h>
#include <hip/hip_bf16.h>

// MHA forward: B=2, S=2048, D=1024, H=16, HD=64. f32 in/out, bf16 MFMA internally.
constexpr int NH   = 16;
constexpr int SEQ  = 2048;
constexpr int DM   = 1024;
constexpr int HDIM = 64;

typedef __attribute__((ext_vector_type(4))) float f32x4;
typedef __attribute__((ext_vector_type(8))) short bf16x8;

typedef __attribute__((address_space(3))) unsigned int lds_u32_t;
typedef const __attribute__((address_space(1))) unsigned int glb_u32_t;

__device__ __forceinline__ void gll16(const void* g, void* l) {
  // async global->LDS, 16B/lane. LDS dst must be wave-uniform base + lane*16.
  __builtin_amdgcn_global_load_lds((glb_u32_t*)g, (lds_u32_t*)l, 16, 0, 0);
}

__device__ __forceinline__ ushort f2bf(float f) {
  union { float f; unsigned u; } v; v.f = f;
  unsigned u = v.u;
  return (ushort)((u + 0x7fffu + ((u >> 16) & 1u)) >> 16);  // RNE
}

// ---------------- cast f32 -> bf16 (vectorized, G13) ----------------
__global__ void cast_kernel(const float* __restrict__ src, ushort* __restrict__ dst, int n4) {
  int i = blockIdx.x * blockDim.x + threadIdx.x;
  if (i < n4) {
    const float4 v = reinterpret_cast<const float4*>(src)[i];
    ushort4 o;
    o.x = f2bf(v.x); o.y = f2bf(v.y); o.z = f2bf(v.z); o.w = f2bf(v.w);
    reinterpret_cast<ushort4*>(dst)[i] = o;
  }
}

// ---------------- fused QKV GEMM: [4096,1024] @ [3072,1024]^T ----------------
// m97 structure: 128x128 tile, BK=32, 4 waves each 64x64, global_load_lds w=16.
__global__ __launch_bounds__(256) void gemm_qkv(
    const ushort* __restrict__ A,   // xb [4096][1024]
    const ushort* __restrict__ Bw,  // wqkv [3072][1024] (rows = out features, k-contig)
    const float* __restrict__ bq, const float* __restrict__ bk, const float* __restrict__ bv,
    ushort* __restrict__ qh,   // [b,h,s,hd]
    ushort* __restrict__ kh,   // [b,h,s,hd]
    ushort* __restrict__ vth)  // [b,h,hd,s]  (V transposed for PV B-operand)
{
  __shared__ ushort As[128 * 32];
  __shared__ ushort Bs[128 * 32];
  const int tid = threadIdx.x;
  const int lane = tid & 63, wid = tid >> 6;
  const int wr = wid >> 1, wc = wid & 1;
  const int l15 = lane & 15, lhi = lane >> 4;
  const int bm = blockIdx.x, bn = blockIdx.y;

  f32x4 acc[4][4] = {};

  const int strow = tid >> 2;          // staging row 0..63 (chunk covers 64 rows)
  const int stcol = (tid & 3) * 8;     // ushort col offset
  const ushort* Ag0 = A  + (size_t)(bm * 128 + strow) * 1024 + stcol;
  const ushort* Ag1 = Ag0 + 64 * 1024;
  const ushort* Bg0 = Bw + (size_t)(bn * 128 + strow) * 1024 + stcol;
  const ushort* Bg1 = Bg0 + 64 * 1024;
  ushort* Asl = As + tid * 8;
  ushort* Bsl = Bs + tid * 8;

  for (int k0 = 0; k0 < 1024; k0 += 32) {
    gll16(Ag0 + k0, Asl);
    gll16(Ag1 + k0, Asl + 2048);
    gll16(Bg0 + k0, Bsl);
    gll16(Bg1 + k0, Bsl + 2048);
    __syncthreads();  // drains vmcnt(0) before barrier
    bf16x8 af[4], bf[4];
#pragma unroll
    for (int i = 0; i < 4; i++)
      af[i] = *reinterpret_cast<const bf16x8*>(As + (wr * 64 + i * 16 + l15) * 32 + lhi * 8);
#pragma unroll
    for (int j = 0; j < 4; j++)
      bf[j] = *reinterpret_cast<const bf16x8*>(Bs + (wc * 64 + j * 16 + l15) * 32 + lhi * 8);
#pragma unroll
    for (int i = 0; i < 4; i++)
#pragma unroll
      for (int j = 0; j < 4; j++)
        acc[i][j] = __builtin_amdgcn_mfma_f32_16x16x32_bf16(af[i], bf[j], acc[i][j], 0, 0, 0);
    __syncthreads();  // all reads done before next stage overwrites
  }

  // epilogue: scatter per-head, bf16. C/D layout: col=lane&15, row=(lane>>4)*4+reg.
  const int ncol0 = bn * 128 + wc * 64;
  const int mrow0 = bm * 128 + wr * 64;
#pragma unroll
  for (int i = 0; i < 4; i++) {
#pragma unroll
    for (int j = 0; j < 4; j++) {
      const int n = ncol0 + j * 16 + l15;
      const int which = n >> 10;      // 0=q 1=k 2=v (block cols never straddle)
      const int nn = n & 1023;
      const float bias = (which == 0) ? bq[nn] : ((which == 1) ? bk[nn] : bv[nn]);
      const int h = nn >> 6, hd = nn & 63;
#pragma unroll
      for (int jr = 0; jr < 4; jr++) {
        const int m = mrow0 + i * 16 + lhi * 4 + jr;
        const int b = m >> 11, s = m & 2047;
        const ushort val = f2bf(acc[i][j][jr] + bias);
        if (which == 0)
          qh[((size_t)(b * NH + h) * SEQ + s) * HDIM + hd] = val;
        else if (which == 1)
          kh[((size_t)(b * NH + h) * SEQ + s) * HDIM + hd] = val;
        else
          vth[((size_t)(b * NH + h) * HDIM + hd) * SEQ + s] = val;
      }
    }
  }
}

// ---------------- flash attention ----------------
// 4 waves/block; block = 128 q-rows (wave owns 32), KV-tile = 64. Online softmax.
// All 128B-row LDS tiles XOR-swizzled (byte ^= (row&7)<<4) on BOTH source & read.
__global__ __launch_bounds__(256) void attn_kernel(
    const ushort* __restrict__ qh, const ushort* __restrict__ kh,
    const ushort* __restrict__ vth, ushort* __restrict__ ctx)  // ctx [b,s,h*64+hd] bf16
{
  __shared__ ushort Kt[64 * 64];       // [kv][d] swizzled
  __shared__ ushort Vt[64 * 64];       // [d][kv] swizzled
  __shared__ ushort Pl[4][32 * 64];    // per-wave P, swizzled
  const int tid = threadIdx.x, lane = tid & 63, wid = tid >> 6;
  const int l15 = lane & 15, lhi = lane >> 4;
  const int bh = blockIdx.y;           // b*16+h
  const int q0 = blockIdx.x * 128;

  // Q fragments from global (once): row = q, k-dim = d
  bf16x8 qf[2][2];
  const ushort* qb = qh + (size_t)bh * SEQ * HDIM;
#pragma unroll
  for (int i = 0; i < 2; i++)
#pragma unroll
    for (int ks = 0; ks < 2; ks++)
      qf[i][ks] = *reinterpret_cast<const bf16x8*>(
          qb + (size_t)(q0 + wid * 32 + i * 16 + l15) * HDIM + ks * 32 + lhi * 8);

  f32x4 o[2][4] = {};
  float mrow[2][4], lrow[2][4];
#pragma unroll
  for (int i = 0; i < 2; i++)
#pragma unroll
    for (int jr = 0; jr < 4; jr++) { mrow[i][jr] = -INFINITY; lrow[i][jr] = 0.f; }

  const int srow = tid >> 3;           // staging row 0..31 per 4KB chunk
  const int scolb = (tid & 7) * 16;    // byte col within 128B row
  const int sswz = (srow & 7) << 4;    // (srow+32)&7 == srow&7
  const ushort* kbase = kh + (size_t)bh * SEQ * HDIM;
  const ushort* vbase = vth + (size_t)bh * HDIM * SEQ;

  for (int kv0 = 0; kv0 < SEQ; kv0 += 64) {
    // stage K [64][64] and Vt [64][64]; pre-swizzle the GLOBAL source col (m173)
    gll16(kbase + (size_t)(kv0 + srow) * HDIM + ((scolb ^ sswz) >> 1), Kt + tid * 8);
    gll16(kbase + (size_t)(kv0 + srow + 32) * HDIM + ((scolb ^ sswz) >> 1), Kt + tid * 8 + 2048);
    gll16(vbase + (size_t)srow * SEQ + kv0 + ((scolb ^ sswz) >> 1), Vt + tid * 8);
    gll16(vbase + (size_t)(srow + 32) * SEQ + kv0 + ((scolb ^ sswz) >> 1), Vt + tid * 8 + 2048);
    __syncthreads();

    // QK^T: scores[32 q][64 kv] per wave
    f32x4 sc[2][4] = {};
    bf16x8 bkf[4][2];
#pragma unroll
    for (int j = 0; j < 4; j++) {
      const int row = j * 16 + l15;
      const int swz = (row & 7) << 4;
#pragma unroll
      for (int ks = 0; ks < 2; ks++)
        bkf[j][ks] = *reinterpret_cast<const bf16x8*>(
            (const char*)Kt + row * 128 + ((ks * 64 + lhi * 16) ^ swz));
    }
#pragma unroll
    for (int i = 0; i < 2; i++)
#pragma unroll
      for (int j = 0; j < 4; j++)
#pragma unroll
        for (int ks = 0; ks < 2; ks++)
          sc[i][j] = __builtin_amdgcn_mfma_f32_16x16x32_bf16(qf[i][ks], bkf[j][ks], sc[i][j], 0, 0, 0);

    // online softmax; rows live in 16-lane groups (col = lane&15)
#pragma unroll
    for (int i = 0; i < 2; i++) {
#pragma unroll
      for (int jr = 0; jr < 4; jr++) {
        float s0 = sc[i][0][jr] * 0.125f, s1 = sc[i][1][jr] * 0.125f;
        float s2 = sc[i][2][jr] * 0.125f, s3 = sc[i][3][jr] * 0.125f;
        float mx = fmaxf(fmaxf(s0, s1), fmaxf(s2, s3));
#pragma unroll
        for (int d = 1; d < 16; d <<= 1) mx = fmaxf(mx, __shfl_xor(mx, d));
        const float mnew = fmaxf(mrow[i][jr], mx);
        const float alpha = __expf(mrow[i][jr] - mnew);  // first iter: exp(-inf)=0
        mrow[i][jr] = mnew;
        const float p0 = __expf(s0 - mnew), p1 = __expf(s1 - mnew);
        const float p2 = __expf(s2 - mnew), p3 = __expf(s3 - mnew);
        float rs = p0 + p1 + p2 + p3;
#pragma unroll
        for (int d = 1; d < 16; d <<= 1) rs += __shfl_xor(rs, d);
        lrow[i][jr] = lrow[i][jr] * alpha + rs;
#pragma unroll
        for (int jd = 0; jd < 4; jd++) o[i][jd][jr] *= alpha;
        // write P (C-layout -> LDS, swizzled); wave-private region, no barrier needed
        const int prow = i * 16 + lhi * 4 + jr;
        char* pbase = (char*)Pl[wid] + prow * 128;
        const int swz = (prow & 7) << 4;
        *(ushort*)(pbase + ((0 * 32 + l15 * 2) ^ swz)) = f2bf(p0);
        *(ushort*)(pbase + ((1 * 32 + l15 * 2) ^ swz)) = f2bf(p1);
        *(ushort*)(pbase + ((2 * 32 + l15 * 2) ^ swz)) = f2bf(p2);
        *(ushort*)(pbase + ((3 * 32 + l15 * 2) ^ swz)) = f2bf(p3);
      }
    }

    // PV: O[32 q][64 d] += P[32][64] @ V[64][64]
    bf16x8 ap[2][2], bvf[4][2];
#pragma unroll
    for (int i = 0; i < 2; i++) {
      const int row = i * 16 + l15;
      const int swz = (row & 7) << 4;
#pragma unroll
      for (int ks = 0; ks < 2; ks++)
        ap[i][ks] = *reinterpret_cast<const bf16x8*>(
            (const char*)Pl[wid] + row * 128 + ((ks * 64 + lhi * 16) ^ swz));
    }
#pragma unroll
    for (int jd = 0; jd < 4; jd++) {
      const int row = jd * 16 + l15;
      const int swz = (row & 7) << 4;
#pragma unroll
      for (int ks = 0; ks < 2; ks++)
        bvf[jd][ks] = *reinterpret_cast<const bf16x8*>(
            (const char*)Vt + row * 128 + ((ks * 64 + lhi * 16) ^ swz));
    }
#pragma unroll
    for (int i = 0; i < 2; i++)
#pragma unroll
      for (int jd = 0; jd < 4; jd++)
#pragma unroll
        for (int ks = 0; ks < 2; ks++)
          o[i][jd] = __builtin_amdgcn_mfma_f32_16x16x32_bf16(ap[i][ks], bvf[jd][ks], o[i][jd], 0, 0, 0);
    __syncthreads();  // all waves done with Kt/Vt before restage
  }

  // epilogue: ctx[b][q][h*64+d] = O / l
  const int b = bh >> 4, h = bh & 15;
  ushort* cb = ctx + (size_t)b * SEQ * DM + (size_t)h * HDIM;
#pragma unroll
  for (int i = 0; i < 2; i++)
#pragma unroll
    for (int jr = 0; jr < 4; jr++) {
      const float inv = 1.0f / lrow[i][jr];
      const int q = q0 + wid * 32 + i * 16 + lhi * 4 + jr;
#pragma unroll
      for (int jd = 0; jd < 4; jd++)
        cb[(size_t)q * DM + jd * 16 + l15] = f2bf(o[i][jd][jr] * inv);
    }
}

// ---------------- output projection: [4096,1024] @ [1024,1024]^T + bo, f32 out ----------------
__global__ __launch_bounds__(256) void gemm_out(
    const ushort* __restrict__ A,   // ctx bf16 [4096][1024]
    const ushort* __restrict__ Bw,  // wob [1024][1024]
    const float* __restrict__ bo, float* __restrict__ out)
{
  __shared__ ushort As[128 * 32];
  __shared__ ushort Bs[128 * 32];
  const int tid = threadIdx.x;
  const int lane = tid & 63, wid = tid >> 6;
  const int wr = wid >> 1, wc = wid & 1;
  const int l15 = lane & 15, lhi = lane >> 4;
  const int bm = blockIdx.x, bn = blockIdx.y;

  f32x4 acc[4][4] = {};

  const int strow = tid >> 2;
  const int stcol = (tid & 3) * 8;
  const ushort* Ag0 = A  + (size_t)(bm * 128 + strow) * 1024 + stcol;
  const ushort* Ag1 = Ag0 + 64 * 1024;
  const ushort* Bg0 = Bw + (size_t)(bn * 128 + strow) * 1024 + stcol;
  const ushort* Bg1 = Bg0 + 64 * 1024;
  ushort* Asl = As + tid * 8;
  ushort* Bsl = Bs + tid * 8;

  for (int k0 = 0; k0 < 1024; k0 += 32) {
    gll16(Ag0 + k0, Asl);
    gll16(Ag1 + k0, Asl + 2048);
    gll16(Bg0 + k0, Bsl);
    gll16(Bg1 + k0, Bsl + 2048);
    __syncthreads();
    bf16x8 af[4], bf[4];
#pragma unroll
    for (int i = 0; i < 4; i++)
      af[i] = *reinterpret_cast<const bf16x8*>(As + (wr * 64 + i * 16 + l15) * 32 + lhi * 8);
#pragma unroll
    for (int j = 0; j < 4; j++)
      bf[j] = *reinterpret_cast<const bf16x8*>(Bs + (wc * 64 + j * 16 + l15) * 32 + lhi * 8);
#pragma unroll
    for (int i = 0; i < 4; i++)
#pragma unroll
      for (int j = 0; j < 4; j++)
        acc[i][j] = __builtin_amdgcn_mfma_f32_16x16x32_bf16(af[i], bf[j], acc[i][j], 0, 0, 0);
    __syncthreads();
  }

  const int ncol0 = bn * 128 + wc * 64;
  const int mrow0 = bm * 128 + wr * 64;
#pragma unroll
  for (int i = 0; i < 4; i++)
#pragma unroll
    for (int j = 0; j < 4; j++) {
      const int n = ncol0 + j * 16 + l15;
      const float bias = bo[n];
#pragma unroll
      for (int jr = 0; jr < 4; jr++) {
        const int m = mrow0 + i * 16 + lhi * 4 + jr;
        out[(size_t)m * 1024 + n] = acc[i][j][jr] + bias;
      }
    }
}

extern "C" void kernel_launch(void* const* d_in, const int* in_sizes, int n_in,
                              void* d_out, int out_size, void* d_ws, size_t ws_size,
                              hipStream_t stream) {
  (void)in_sizes; (void)n_in; (void)out_size; (void)ws_size;
  const float* x  = (const float*)d_in[0];
  const float* Wq = (const float*)d_in[1];
  const float* bq = (const float*)d_in[2];
  const float* Wk = (const float*)d_in[3];
  const float* bk = (const float*)d_in[4];
  const float* Wv = (const float*)d_in[5];
  const float* bv = (const float*)d_in[6];
  const float* Wo = (const float*)d_in[7];
  const float* bo = (const float*)d_in[8];
  float* out = (float*)d_out;

  // workspace layout (bytes): 48 MB total
  char* ws = (char*)d_ws;
  ushort* xb   = (ushort*)(ws);               // 8 MB   [4096][1024] bf16
  ushort* wqkv = (ushort*)(ws + 8388608);     // 6 MB   [3072][1024]
  ushort* wob  = (ushort*)(ws + 14680064);    // 2 MB   [1024][1024]
  ushort* qhb  = (ushort*)(ws + 16777216);    // 8 MB   [b,h,s,hd]
  ushort* khb  = (ushort*)(ws + 25165824);    // 8 MB   [b,h,s,hd]
  ushort* vth  = (ushort*)(ws + 33554432);    // 8 MB   [b,h,hd,s]
  ushort* ctx  = (ushort*)(ws + 41943040);    // 8 MB   [b,s,d]

  cast_kernel<<<4096, 256, 0, stream>>>(x, xb, 1048576);
  cast_kernel<<<1024, 256, 0, stream>>>(Wq, wqkv, 262144);
  cast_kernel<<<1024, 256, 0, stream>>>(Wk, wqkv + 1048576, 262144);
  cast_kernel<<<1024, 256, 0, stream>>>(Wv, wqkv + 2097152, 262144);
  cast_kernel<<<1024, 256, 0, stream>>>(Wo, wob, 262144);
  gemm_qkv<<<dim3(32, 24), 256, 0, stream>>>(xb, wqkv, bq, bk, bv, qhb, khb, vth);
  attn_kernel<<<dim3(16, 32), 256, 0, stream>>>(qhb, khb, vth, ctx);
  gemm_out<<<dim3(32, 8), 256, 0, stream>>>(ctx, wob, bo, out);
}

// Round 3
// 264.815 us; speedup vs baseline: 1.0362x; 1.0362x over previous
//
#include <hip/hip_runtime.h>
#include <hip/hip_bf16.h>

// MHA forward: B=2, S=2048, D=1024, H=16, HD=64. f32 in/out, bf16 MFMA internally.
constexpr int NH   = 16;
constexpr int SEQ  = 2048;
constexpr int DM   = 1024;
constexpr int HDIM = 64;

typedef __attribute__((ext_vector_type(4))) float f32x4;
typedef __attribute__((ext_vector_type(8))) short bf16x8;

typedef __attribute__((address_space(3))) unsigned int lds_u32_t;
typedef const __attribute__((address_space(1))) unsigned int glb_u32_t;

__device__ __forceinline__ void gll16(const void* g, void* l) {
  // async global->LDS, 16B/lane. LDS dst must be wave-uniform base + lane*16.
  __builtin_amdgcn_global_load_lds((glb_u32_t*)g, (lds_u32_t*)l, 16, 0, 0);
}

__device__ __forceinline__ ushort f2bf(float f) {
  union { float f; unsigned u; } v; v.f = f;
  unsigned u = v.u;
  return (ushort)((u + 0x7fffu + ((u >> 16) & 1u)) >> 16);  // RNE
}

__device__ __forceinline__ ushort f2bf_trunc(float f) {
  union { float f; unsigned u; } v; v.f = f;
  return (ushort)(v.u >> 16);  // truncation: 1 op, P in [0,256] tolerates it
}

__device__ __forceinline__ float fast_exp2(float x) {
#if __has_builtin(__builtin_amdgcn_exp2f)
  return __builtin_amdgcn_exp2f(x);   // raw v_exp_f32 (2^x)
#else
  return __expf(x * 0.69314718056f);  // exp(x*ln2) == 2^x; costs one extra mul
#endif
}

// ---------------- single cast kernel: all 5 f32->bf16 tensors ----------------
__global__ void cast_all(const float* __restrict__ x,
                         const float* __restrict__ wq, const float* __restrict__ wk,
                         const float* __restrict__ wv, const float* __restrict__ wo,
                         ushort* __restrict__ xb, ushort* __restrict__ wqkv,
                         ushort* __restrict__ wob) {
  const int i = blockIdx.x * blockDim.x + threadIdx.x;  // float4 index, total 2097152
  const float* src; ushort* dst; int off;
  if (i < 1048576)      { src = x;  dst = xb;             off = i; }
  else if (i < 1310720) { src = wq; dst = wqkv;           off = i - 1048576; }
  else if (i < 1572864) { src = wk; dst = wqkv + 1048576; off = i - 1310720; }
  else if (i < 1835008) { src = wv; dst = wqkv + 2097152; off = i - 1572864; }
  else                  { src = wo; dst = wob;            off = i - 1835008; }
  const float4 v = reinterpret_cast<const float4*>(src)[off];
  ushort4 o;
  o.x = f2bf(v.x); o.y = f2bf(v.y); o.z = f2bf(v.z); o.w = f2bf(v.w);
  reinterpret_cast<ushort4*>(dst)[off] = o;
}

// ---------------- fused QKV GEMM: [4096,1024] @ [3072,1024]^T ----------------
// m97 structure: 128x128 tile, BK=32, 4 waves each 64x64, global_load_lds w=16.
// Q outputs are pre-scaled by 0.125*log2(e) so attn softmax runs in exp2-domain.
__global__ __launch_bounds__(256) void gemm_qkv(
    const ushort* __restrict__ A,   // xb [4096][1024]
    const ushort* __restrict__ Bw,  // wqkv [3072][1024] (rows = out features, k-contig)
    const float* __restrict__ bq, const float* __restrict__ bk, const float* __restrict__ bv,
    ushort* __restrict__ qh,   // [b,h,s,hd]  (pre-scaled)
    ushort* __restrict__ kh,   // [b,h,s,hd]
    ushort* __restrict__ vth)  // [b,h,hd,s]  (V transposed for PV B-operand)
{
  __shared__ ushort As[128 * 32];
  __shared__ ushort Bs[128 * 32];
  const int tid = threadIdx.x;
  const int lane = tid & 63, wid = tid >> 6;
  const int wr = wid >> 1, wc = wid & 1;
  const int l15 = lane & 15, lhi = lane >> 4;
  const int bm = blockIdx.x, bn = blockIdx.y;

  f32x4 acc[4][4] = {};

  const int strow = tid >> 2;          // staging row 0..63 (chunk covers 64 rows)
  const int stcol = (tid & 3) * 8;     // ushort col offset
  const ushort* Ag0 = A  + (size_t)(bm * 128 + strow) * 1024 + stcol;
  const ushort* Ag1 = Ag0 + 64 * 1024;
  const ushort* Bg0 = Bw + (size_t)(bn * 128 + strow) * 1024 + stcol;
  const ushort* Bg1 = Bg0 + 64 * 1024;
  ushort* Asl = As + tid * 8;
  ushort* Bsl = Bs + tid * 8;

  for (int k0 = 0; k0 < 1024; k0 += 32) {
    gll16(Ag0 + k0, Asl);
    gll16(Ag1 + k0, Asl + 2048);
    gll16(Bg0 + k0, Bsl);
    gll16(Bg1 + k0, Bsl + 2048);
    __syncthreads();  // drains vmcnt(0) before barrier
    bf16x8 af[4], bf[4];
#pragma unroll
    for (int i = 0; i < 4; i++)
      af[i] = *reinterpret_cast<const bf16x8*>(As + (wr * 64 + i * 16 + l15) * 32 + lhi * 8);
#pragma unroll
    for (int j = 0; j < 4; j++)
      bf[j] = *reinterpret_cast<const bf16x8*>(Bs + (wc * 64 + j * 16 + l15) * 32 + lhi * 8);
#pragma unroll
    for (int i = 0; i < 4; i++)
#pragma unroll
      for (int j = 0; j < 4; j++)
        acc[i][j] = __builtin_amdgcn_mfma_f32_16x16x32_bf16(af[i], bf[j], acc[i][j], 0, 0, 0);
    __syncthreads();  // all reads done before next stage overwrites
  }

  // epilogue: scatter per-head, bf16. C/D layout: col=lane&15, row=(lane>>4)*4+reg.
  // A wave's 64-col span aligns with one head group and never straddles q/k/v.
  const int ncol0 = bn * 128 + wc * 64;
  const int mrow0 = bm * 128 + wr * 64;
  const int which = ncol0 >> 10;  // 0=q 1=k 2=v

  if (which == 2) {
    // V: transposed layout, pack 4 consecutive-s bf16 into one 8B store
#pragma unroll
    for (int i = 0; i < 4; i++) {
#pragma unroll
      for (int j = 0; j < 4; j++) {
        const int nn = (ncol0 + j * 16 + l15) & 1023;
        const int h = nn >> 6, hd = nn & 63;
        const float bias = bv[nn];
        const int m0 = mrow0 + i * 16 + lhi * 4;   // 4 consecutive s, never cross b
        const int b = m0 >> 11, s = m0 & 2047;
        ushort4 pk;
        pk.x = f2bf(acc[i][j][0] + bias);
        pk.y = f2bf(acc[i][j][1] + bias);
        pk.z = f2bf(acc[i][j][2] + bias);
        pk.w = f2bf(acc[i][j][3] + bias);
        *reinterpret_cast<ushort4*>(
            &vth[((size_t)(b * NH + h) * HDIM + hd) * SEQ + s]) = pk;
      }
    }
  } else {
    const float scl = (which == 0) ? 0.18033688f : 1.0f;  // 0.125 * log2(e) baked into Q
    const float* __restrict__ bptr = (which == 0) ? bq : bk;
    ushort* __restrict__ dst = (which == 0) ? qh : kh;
#pragma unroll
    for (int i = 0; i < 4; i++) {
#pragma unroll
      for (int j = 0; j < 4; j++) {
        const int nn = (ncol0 + j * 16 + l15) & 1023;
        const int h = nn >> 6, hd = nn & 63;
        const float bias = bptr[nn];
#pragma unroll
        for (int jr = 0; jr < 4; jr++) {
          const int m = mrow0 + i * 16 + lhi * 4 + jr;
          const int b = m >> 11, s = m & 2047;
          dst[((size_t)(b * NH + h) * SEQ + s) * HDIM + hd] = f2bf((acc[i][j][jr] + bias) * scl);
        }
      }
    }
  }
}

// ---------------- flash attention ----------------
// 4 waves/block; block = 128 q-rows (wave owns 32), KV-tile = 64. Online softmax
// in exp2-domain (scale baked into Q). Double-buffered K/V with issue-early
// prefetch (T3-minimum): one barrier per tile. Defer-rescale THR=8 (T13).
// All 128B-row LDS tiles XOR-swizzled (byte ^= (row&7)<<4) on BOTH source & read.
__global__ __launch_bounds__(256) void attn_kernel(
    const ushort* __restrict__ qh, const ushort* __restrict__ kh,
    const ushort* __restrict__ vth, ushort* __restrict__ ctx)  // ctx [b,s,h*64+hd] bf16
{
  __shared__ ushort Kt[2][64 * 64];    // [kv][d] swizzled, double-buffered
  __shared__ ushort Vt[2][64 * 64];    // [d][kv] swizzled, double-buffered
  __shared__ ushort Pl[4][32 * 64];    // per-wave P, swizzled
  const int tid = threadIdx.x, lane = tid & 63, wid = tid >> 6;
  const int l15 = lane & 15, lhi = lane >> 4;
  const int bh = blockIdx.y;           // b*16+h
  const int q0 = blockIdx.x * 128;

  // Q fragments from global (once): row = q, k-dim = d. Pre-scaled by 0.125*log2e.
  bf16x8 qf[2][2];
  const ushort* qb = qh + (size_t)bh * SEQ * HDIM;
#pragma unroll
  for (int i = 0; i < 2; i++)
#pragma unroll
    for (int ks = 0; ks < 2; ks++)
      qf[i][ks] = *reinterpret_cast<const bf16x8*>(
          qb + (size_t)(q0 + wid * 32 + i * 16 + l15) * HDIM + ks * 32 + lhi * 8);

  f32x4 o[2][4] = {};
  float mrow[2][4], lrow[2][4];
#pragma unroll
  for (int i = 0; i < 2; i++)
#pragma unroll
    for (int jr = 0; jr < 4; jr++) { mrow[i][jr] = -INFINITY; lrow[i][jr] = 0.f; }

  const int srow = tid >> 3;           // staging row 0..31 per 4KB chunk
  const int scolb = (tid & 7) * 16;    // byte col within 128B row
  const int sswz = (srow & 7) << 4;    // (srow+32)&7 == srow&7
  const int scole = (scolb ^ sswz) >> 1;  // pre-swizzled source col (elements)
  const ushort* kbase = kh + (size_t)bh * SEQ * HDIM;
  const ushort* vbase = vth + (size_t)bh * HDIM * SEQ;

  // issue K/V stage for tile starting at kv0 into buffer `buf`
  auto stage = [&](int buf, int kv0) {
    gll16(kbase + (size_t)(kv0 + srow) * HDIM + scole, &Kt[buf][tid * 8]);
    gll16(kbase + (size_t)(kv0 + srow + 32) * HDIM + scole, &Kt[buf][tid * 8 + 2048]);
    gll16(vbase + (size_t)srow * SEQ + kv0 + scole, &Vt[buf][tid * 8]);
    gll16(vbase + (size_t)(srow + 32) * SEQ + kv0 + scole, &Vt[buf][tid * 8 + 2048]);
  };

  stage(0, 0);
  __syncthreads();  // vmcnt(0) drain + barrier: buf0 ready

  for (int t = 0; t < SEQ / 64; ++t) {
    const int cur = t & 1;
    if (t < SEQ / 64 - 1) stage(cur ^ 1, (t + 1) * 64);  // issue-early prefetch

    // QK^T: scores[32 q][64 kv] per wave (already in exp2-domain units)
    f32x4 sc[2][4] = {};
    bf16x8 bkf[4][2];
#pragma unroll
    for (int j = 0; j < 4; j++) {
      const int row = j * 16 + l15;
      const int swz = (row & 7) << 4;
#pragma unroll
      for (int ks = 0; ks < 2; ks++)
        bkf[j][ks] = *reinterpret_cast<const bf16x8*>(
            (const char*)Kt[cur] + row * 128 + ((ks * 64 + lhi * 16) ^ swz));
    }
#pragma unroll
    for (int i = 0; i < 2; i++)
#pragma unroll
      for (int j = 0; j < 4; j++)
#pragma unroll
        for (int ks = 0; ks < 2; ks++)
          sc[i][j] = __builtin_amdgcn_mfma_f32_16x16x32_bf16(qf[i][ks], bkf[j][ks], sc[i][j], 0, 0, 0);

    // --- online softmax (exp2-domain), defer-rescale THR=8 ---
    float mx8[2][4];
    int need = 0;
#pragma unroll
    for (int i = 0; i < 2; i++)
#pragma unroll
      for (int jr = 0; jr < 4; jr++) {
        float mx = fmaxf(fmaxf(sc[i][0][jr], sc[i][1][jr]), fmaxf(sc[i][2][jr], sc[i][3][jr]));
#pragma unroll
        for (int d = 1; d < 16; d <<= 1) mx = fmaxf(mx, __shfl_xor(mx, d));
        mx8[i][jr] = mx;
        need |= (mx > mrow[i][jr] + 8.0f);
      }
    if (__any(need)) {  // rescale path: rare after the first tile
#pragma unroll
      for (int i = 0; i < 2; i++)
#pragma unroll
        for (int jr = 0; jr < 4; jr++) {
          const float mnew = fmaxf(mrow[i][jr], mx8[i][jr]);
          const float alpha = fast_exp2(mrow[i][jr] - mnew);  // first tile: exp2(-inf)=0
          mrow[i][jr] = mnew;
          lrow[i][jr] *= alpha;
#pragma unroll
          for (int jd = 0; jd < 4; jd++) o[i][jd][jr] *= alpha;
        }
    }
#pragma unroll
    for (int i = 0; i < 2; i++) {
#pragma unroll
      for (int jr = 0; jr < 4; jr++) {
        const float m = mrow[i][jr];
        const float p0 = fast_exp2(sc[i][0][jr] - m), p1 = fast_exp2(sc[i][1][jr] - m);
        const float p2 = fast_exp2(sc[i][2][jr] - m), p3 = fast_exp2(sc[i][3][jr] - m);
        float rs = (p0 + p1) + (p2 + p3);
#pragma unroll
        for (int d = 1; d < 16; d <<= 1) rs += __shfl_xor(rs, d);
        lrow[i][jr] += rs;
        // write P (C-layout -> LDS, swizzled); wave-private region, no barrier needed
        const int prow = i * 16 + lhi * 4 + jr;
        char* pbase = (char*)Pl[wid] + prow * 128;
        const int swz = (prow & 7) << 4;
        *(ushort*)(pbase + ((0 * 32 + l15 * 2) ^ swz)) = f2bf_trunc(p0);
        *(ushort*)(pbase + ((1 * 32 + l15 * 2) ^ swz)) = f2bf_trunc(p1);
        *(ushort*)(pbase + ((2 * 32 + l15 * 2) ^ swz)) = f2bf_trunc(p2);
        *(ushort*)(pbase + ((3 * 32 + l15 * 2) ^ swz)) = f2bf_trunc(p3);
      }
    }

    // PV: O[32 q][64 d] += P[32][64] @ V[64][64]
    bf16x8 ap[2][2], bvf[4][2];
#pragma unroll
    for (int i = 0; i < 2; i++) {
      const int row = i * 16 + l15;
      const int swz = (row & 7) << 4;
#pragma unroll
      for (int ks = 0; ks < 2; ks++)
        ap[i][ks] = *reinterpret_cast<const bf16x8*>(
            (const char*)Pl[wid] + row * 128 + ((ks * 64 + lhi * 16) ^ swz));
    }
#pragma unroll
    for (int jd = 0; jd < 4; jd++) {
      const int row = jd * 16 + l15;
      const int swz = (row & 7) << 4;
#pragma unroll
      for (int ks = 0; ks < 2; ks++)
        bvf[jd][ks] = *reinterpret_cast<const bf16x8*>(
            (const char*)Vt[cur] + row * 128 + ((ks * 64 + lhi * 16) ^ swz));
    }
#pragma unroll
    for (int i = 0; i < 2; i++)
#pragma unroll
      for (int jd = 0; jd < 4; jd++)
#pragma unroll
        for (int ks = 0; ks < 2; ks++)
          o[i][jd] = __builtin_amdgcn_mfma_f32_16x16x32_bf16(ap[i][ks], bvf[jd][ks], o[i][jd], 0, 0, 0);

    __syncthreads();  // single barrier/tile: drains vmcnt (next buf ready) + lgkm; all waves done with cur
  }

  // epilogue: ctx[b][q][h*64+d] = O / l
  const int b = bh >> 4, h = bh & 15;
  ushort* cb = ctx + (size_t)b * SEQ * DM + (size_t)h * HDIM;
#pragma unroll
  for (int i = 0; i < 2; i++)
#pragma unroll
    for (int jr = 0; jr < 4; jr++) {
      const float inv = 1.0f / lrow[i][jr];
      const int q = q0 + wid * 32 + i * 16 + lhi * 4 + jr;
#pragma unroll
      for (int jd = 0; jd < 4; jd++)
        cb[(size_t)q * DM + jd * 16 + l15] = f2bf(o[i][jd][jr] * inv);
    }
}

// ---------------- output projection: [4096,1024] @ [1024,1024]^T + bo, f32 out ----------------
__global__ __launch_bounds__(256) void gemm_out(
    const ushort* __restrict__ A,   // ctx bf16 [4096][1024]
    const ushort* __restrict__ Bw,  // wob [1024][1024]
    const float* __restrict__ bo, float* __restrict__ out)
{
  __shared__ ushort As[128 * 32];
  __shared__ ushort Bs[128 * 32];
  const int tid = threadIdx.x;
  const int lane = tid & 63, wid = tid >> 6;
  const int wr = wid >> 1, wc = wid & 1;
  const int l15 = lane & 15, lhi = lane >> 4;
  const int bm = blockIdx.x, bn = blockIdx.y;

  f32x4 acc[4][4] = {};

  const int strow = tid >> 2;
  const int stcol = (tid & 3) * 8;
  const ushort* Ag0 = A  + (size_t)(bm * 128 + strow) * 1024 + stcol;
  const ushort* Ag1 = Ag0 + 64 * 1024;
  const ushort* Bg0 = Bw + (size_t)(bn * 128 + strow) * 1024 + stcol;
  const ushort* Bg1 = Bg0 + 64 * 1024;
  ushort* Asl = As + tid * 8;
  ushort* Bsl = Bs + tid * 8;

  for (int k0 = 0; k0 < 1024; k0 += 32) {
    gll16(Ag0 + k0, Asl);
    gll16(Ag1 + k0, Asl + 2048);
    gll16(Bg0 + k0, Bsl);
    gll16(Bg1 + k0, Bsl + 2048);
    __syncthreads();
    bf16x8 af[4], bf[4];
#pragma unroll
    for (int i = 0; i < 4; i++)
      af[i] = *reinterpret_cast<const bf16x8*>(As + (wr * 64 + i * 16 + l15) * 32 + lhi * 8);
#pragma unroll
    for (int j = 0; j < 4; j++)
      bf[j] = *reinterpret_cast<const bf16x8*>(Bs + (wc * 64 + j * 16 + l15) * 32 + lhi * 8);
#pragma unroll
    for (int i = 0; i < 4; i++)
#pragma unroll
      for (int j = 0; j < 4; j++)
        acc[i][j] = __builtin_amdgcn_mfma_f32_16x16x32_bf16(af[i], bf[j], acc[i][j], 0, 0, 0);
    __syncthreads();
  }

  const int ncol0 = bn * 128 + wc * 64;
  const int mrow0 = bm * 128 + wr * 64;
#pragma unroll
  for (int i = 0; i < 4; i++)
#pragma unroll
    for (int j = 0; j < 4; j++) {
      const int n = ncol0 + j * 16 + l15;
      const float bias = bo[n];
#pragma unroll
      for (int jr = 0; jr < 4; jr++) {
        const int m = mrow0 + i * 16 + lhi * 4 + jr;
        out[(size_t)m * 1024 + n] = acc[i][j][jr] + bias;
      }
    }
}

extern "C" void kernel_launch(void* const* d_in, const int* in_sizes, int n_in,
                              void* d_out, int out_size, void* d_ws, size_t ws_size,
                              hipStream_t stream) {
  (void)in_sizes; (void)n_in; (void)out_size; (void)ws_size;
  const float* x  = (const float*)d_in[0];
  const float* Wq = (const float*)d_in[1];
  const float* bq = (const float*)d_in[2];
  const float* Wk = (const float*)d_in[3];
  const float* bk = (const float*)d_in[4];
  const float* Wv = (const float*)d_in[5];
  const float* bv = (const float*)d_in[6];
  const float* Wo = (const float*)d_in[7];
  const float* bo = (const float*)d_in[8];
  float* out = (float*)d_out;

  // workspace layout (bytes): 48 MB total
  char* ws = (char*)d_ws;
  ushort* xb   = (ushort*)(ws);               // 8 MB   [4096][1024] bf16
  ushort* wqkv = (ushort*)(ws + 8388608);     // 6 MB   [3072][1024]
  ushort* wob  = (ushort*)(ws + 14680064);    // 2 MB   [1024][1024]
  ushort* qhb  = (ushort*)(ws + 16777216);    // 8 MB   [b,h,s,hd]
  ushort* khb  = (ushort*)(ws + 25165824);    // 8 MB   [b,h,s,hd]
  ushort* vth  = (ushort*)(ws + 33554432);    // 8 MB   [b,h,hd,s]
  ushort* ctx  = (ushort*)(ws + 41943040);    // 8 MB   [b,s,d]

  cast_all<<<8192, 256, 0, stream>>>(x, Wq, Wk, Wv, Wo, xb, wqkv, wob);
  gemm_qkv<<<dim3(32, 24), 256, 0, stream>>>(xb, wqkv, bq, bk, bv, qhb, khb, vth);
  attn_kernel<<<dim3(16, 32), 256, 0, stream>>>(qhb, khb, vth, ctx);
  gemm_out<<<dim3(32, 8), 256, 0, stream>>>(ctx, wob, bo, out);
}

// Round 4
// 253.787 us; speedup vs baseline: 1.0812x; 1.0435x over previous
//
#include <hip/hip_runtime.h>
#include <hip/hip_bf16.h>

// MHA forward: B=2, S=2048, D=1024, H=16, HD=64. f32 in/out, bf16 MFMA internally.
constexpr int NH   = 16;
constexpr int SEQ  = 2048;
constexpr int DM   = 1024;
constexpr int HDIM = 64;

typedef __attribute__((ext_vector_type(4))) float f32x4;
typedef __attribute__((ext_vector_type(8))) short bf16x8;

typedef __attribute__((address_space(3))) unsigned int lds_u32_t;
typedef const __attribute__((address_space(1))) unsigned int glb_u32_t;

__device__ __forceinline__ void gll16(const void* g, void* l) {
  // async global->LDS, 16B/lane. LDS dst must be wave-uniform base + lane*16.
  __builtin_amdgcn_global_load_lds((glb_u32_t*)g, (lds_u32_t*)l, 16, 0, 0);
}

__device__ __forceinline__ ushort f2bf(float f) {
  union { float f; unsigned u; } v; v.f = f;
  unsigned u = v.u;
  return (ushort)((u + 0x7fffu + ((u >> 16) & 1u)) >> 16);  // RNE
}

__device__ __forceinline__ ushort f2bf_trunc(float f) {
  union { float f; unsigned u; } v; v.f = f;
  return (ushort)(v.u >> 16);  // truncation: 1 op, P in [0,256] tolerates it
}

__device__ __forceinline__ float fast_exp2(float x) {
#if __has_builtin(__builtin_amdgcn_exp2f)
  return __builtin_amdgcn_exp2f(x);   // raw v_exp_f32 (2^x)
#else
  return __expf(x * 0.69314718056f);  // exp(x*ln2) == 2^x; costs one extra mul
#endif
}

// ---------------- single cast kernel: all 5 f32->bf16 tensors ----------------
__global__ void cast_all(const float* __restrict__ x,
                         const float* __restrict__ wq, const float* __restrict__ wk,
                         const float* __restrict__ wv, const float* __restrict__ wo,
                         ushort* __restrict__ xb, ushort* __restrict__ wqkv,
                         ushort* __restrict__ wob) {
  const int i = blockIdx.x * blockDim.x + threadIdx.x;  // float4 index, total 2097152
  const float* src; ushort* dst; int off;
  if (i < 1048576)      { src = x;  dst = xb;             off = i; }
  else if (i < 1310720) { src = wq; dst = wqkv;           off = i - 1048576; }
  else if (i < 1572864) { src = wk; dst = wqkv + 1048576; off = i - 1310720; }
  else if (i < 1835008) { src = wv; dst = wqkv + 2097152; off = i - 1572864; }
  else                  { src = wo; dst = wob;            off = i - 1835008; }
  const float4 v = reinterpret_cast<const float4*>(src)[off];
  ushort4 o;
  o.x = f2bf(v.x); o.y = f2bf(v.y); o.z = f2bf(v.z); o.w = f2bf(v.w);
  reinterpret_cast<ushort4*>(dst)[off] = o;
}

// ---------------- fused QKV GEMM: [4096,1024] @ [3072,1024]^T ----------------
// m97 structure: 128x128 tile, BK=32, 4 waves each 64x64, global_load_lds w=16.
// Q outputs are pre-scaled by 0.125*log2(e) so attn softmax runs in exp2-domain.
__global__ __launch_bounds__(256) void gemm_qkv(
    const ushort* __restrict__ A,   // xb [4096][1024]
    const ushort* __restrict__ Bw,  // wqkv [3072][1024] (rows = out features, k-contig)
    const float* __restrict__ bq, const float* __restrict__ bk, const float* __restrict__ bv,
    ushort* __restrict__ qh,   // [b,h,s,hd]  (pre-scaled)
    ushort* __restrict__ kh,   // [b,h,s,hd]
    ushort* __restrict__ vth)  // [b,h,hd,s]  (V transposed for PV B-operand)
{
  __shared__ ushort As[128 * 32];
  __shared__ ushort Bs[128 * 32];
  const int tid = threadIdx.x;
  const int lane = tid & 63, wid = tid >> 6;
  const int wr = wid >> 1, wc = wid & 1;
  const int l15 = lane & 15, lhi = lane >> 4;
  const int bm = blockIdx.x, bn = blockIdx.y;

  f32x4 acc[4][4] = {};

  const int strow = tid >> 2;          // staging row 0..63 (chunk covers 64 rows)
  const int stcol = (tid & 3) * 8;     // ushort col offset
  const ushort* Ag0 = A  + (size_t)(bm * 128 + strow) * 1024 + stcol;
  const ushort* Ag1 = Ag0 + 64 * 1024;
  const ushort* Bg0 = Bw + (size_t)(bn * 128 + strow) * 1024 + stcol;
  const ushort* Bg1 = Bg0 + 64 * 1024;
  ushort* Asl = As + tid * 8;
  ushort* Bsl = Bs + tid * 8;

  for (int k0 = 0; k0 < 1024; k0 += 32) {
    gll16(Ag0 + k0, Asl);
    gll16(Ag1 + k0, Asl + 2048);
    gll16(Bg0 + k0, Bsl);
    gll16(Bg1 + k0, Bsl + 2048);
    __syncthreads();  // drains vmcnt(0) before barrier
    bf16x8 af[4], bf[4];
#pragma unroll
    for (int i = 0; i < 4; i++)
      af[i] = *reinterpret_cast<const bf16x8*>(As + (wr * 64 + i * 16 + l15) * 32 + lhi * 8);
#pragma unroll
    for (int j = 0; j < 4; j++)
      bf[j] = *reinterpret_cast<const bf16x8*>(Bs + (wc * 64 + j * 16 + l15) * 32 + lhi * 8);
#pragma unroll
    for (int i = 0; i < 4; i++)
#pragma unroll
      for (int j = 0; j < 4; j++)
        acc[i][j] = __builtin_amdgcn_mfma_f32_16x16x32_bf16(af[i], bf[j], acc[i][j], 0, 0, 0);
    __syncthreads();  // all reads done before next stage overwrites
  }

  // epilogue: scatter per-head, bf16. C/D layout: col=lane&15, row=(lane>>4)*4+reg.
  // A wave's 64-col span aligns with one head group and never straddles q/k/v.
  const int ncol0 = bn * 128 + wc * 64;
  const int mrow0 = bm * 128 + wr * 64;
  const int which = ncol0 >> 10;  // 0=q 1=k 2=v

  if (which == 2) {
    // V: transposed layout, pack 4 consecutive-s bf16 into one 8B store
#pragma unroll
    for (int i = 0; i < 4; i++) {
#pragma unroll
      for (int j = 0; j < 4; j++) {
        const int nn = (ncol0 + j * 16 + l15) & 1023;
        const int h = nn >> 6, hd = nn & 63;
        const float bias = bv[nn];
        const int m0 = mrow0 + i * 16 + lhi * 4;   // 4 consecutive s, never cross b
        const int b = m0 >> 11, s = m0 & 2047;
        ushort4 pk;
        pk.x = f2bf(acc[i][j][0] + bias);
        pk.y = f2bf(acc[i][j][1] + bias);
        pk.z = f2bf(acc[i][j][2] + bias);
        pk.w = f2bf(acc[i][j][3] + bias);
        *reinterpret_cast<ushort4*>(
            &vth[((size_t)(b * NH + h) * HDIM + hd) * SEQ + s]) = pk;
      }
    }
  } else {
    const float scl = (which == 0) ? 0.18033688f : 1.0f;  // 0.125 * log2(e) baked into Q
    const float* __restrict__ bptr = (which == 0) ? bq : bk;
    ushort* __restrict__ dst = (which == 0) ? qh : kh;
#pragma unroll
    for (int i = 0; i < 4; i++) {
#pragma unroll
      for (int j = 0; j < 4; j++) {
        const int nn = (ncol0 + j * 16 + l15) & 1023;
        const int h = nn >> 6, hd = nn & 63;
        const float bias = bptr[nn];
#pragma unroll
        for (int jr = 0; jr < 4; jr++) {
          const int m = mrow0 + i * 16 + lhi * 4 + jr;
          const int b = m >> 11, s = m & 2047;
          dst[((size_t)(b * NH + h) * SEQ + s) * HDIM + hd] = f2bf((acc[i][j][jr] + bias) * scl);
        }
      }
    }
  }
}

// ---------------- flash attention ----------------
// 8 waves/block (512 thr); block = 128 q-rows, wave owns 16. KV-tile = 64.
// 2 blocks/CU x 8 waves = 4 waves/SIMD (2x the round-3 TLP) to hide the
// softmax serial chains. Online softmax in exp2-domain; double-buffered K/V
// issue-early prefetch; defer-rescale THR=8. All 128B-row LDS tiles
// XOR-swizzled (byte ^= (row&7)<<4) on BOTH source & read.
__global__ __launch_bounds__(512, 4) void attn_kernel(
    const ushort* __restrict__ qh, const ushort* __restrict__ kh,
    const ushort* __restrict__ vth, ushort* __restrict__ ctx)  // ctx [b,s,h*64+hd] bf16
{
  __shared__ ushort Kt[2][64 * 64];    // [kv][d] swizzled, double-buffered
  __shared__ ushort Vt[2][64 * 64];    // [d][kv] swizzled, double-buffered
  __shared__ ushort Pl[8][16 * 64];    // per-wave P (16 q-rows), swizzled
  const int tid = threadIdx.x, lane = tid & 63, wid = tid >> 6;
  const int l15 = lane & 15, lhi = lane >> 4;
  const int bh = blockIdx.y;           // b*16+h
  const int q0 = blockIdx.x * 128;
  const int qw = q0 + wid * 16;        // this wave's 16 q-rows

  // Q fragments from global (once): row = q, k-dim = d. Pre-scaled by 0.125*log2e.
  bf16x8 qf[2];
  const ushort* qb = qh + (size_t)bh * SEQ * HDIM;
#pragma unroll
  for (int ks = 0; ks < 2; ks++)
    qf[ks] = *reinterpret_cast<const bf16x8*>(
        qb + (size_t)(qw + l15) * HDIM + ks * 32 + lhi * 8);

  f32x4 o[4] = {};
  float mrow[4], lrow[4];
#pragma unroll
  for (int jr = 0; jr < 4; jr++) { mrow[jr] = -INFINITY; lrow[jr] = 0.f; }

  const int srow = tid >> 3;           // staging row 0..63 (512 thr cover 8KB tile)
  const int scolb = (tid & 7) * 16;    // byte col within 128B row
  const int sswz = (srow & 7) << 4;
  const int scole = (scolb ^ sswz) >> 1;  // pre-swizzled source col (elements)
  const ushort* kbase = kh + (size_t)bh * SEQ * HDIM;
  const ushort* vbase = vth + (size_t)bh * HDIM * SEQ;

  // issue K/V stage for tile starting at kv0 into buffer `buf` (one call each)
  auto stage = [&](int buf, int kv0) {
    gll16(kbase + (size_t)(kv0 + srow) * HDIM + scole, &Kt[buf][tid * 8]);
    gll16(vbase + (size_t)srow * SEQ + kv0 + scole, &Vt[buf][tid * 8]);
  };

  stage(0, 0);
  __syncthreads();  // vmcnt(0) drain + barrier: buf0 ready

  for (int t = 0; t < SEQ / 64; ++t) {
    const int cur = t & 1;
    if (t < SEQ / 64 - 1) stage(cur ^ 1, (t + 1) * 64);  // issue-early prefetch

    // QK^T: scores[16 q][64 kv] per wave (already in exp2-domain units)
    f32x4 sc[4] = {};
    bf16x8 bkf[4][2];
#pragma unroll
    for (int j = 0; j < 4; j++) {
      const int row = j * 16 + l15;
      const int swz = (row & 7) << 4;
#pragma unroll
      for (int ks = 0; ks < 2; ks++)
        bkf[j][ks] = *reinterpret_cast<const bf16x8*>(
            (const char*)Kt[cur] + row * 128 + ((ks * 64 + lhi * 16) ^ swz));
    }
#pragma unroll
    for (int j = 0; j < 4; j++)
#pragma unroll
      for (int ks = 0; ks < 2; ks++)
        sc[j] = __builtin_amdgcn_mfma_f32_16x16x32_bf16(qf[ks], bkf[j][ks], sc[j], 0, 0, 0);

    // --- online softmax (exp2-domain), defer-rescale THR=8 ---
    float mx8[4];
    int need = 0;
#pragma unroll
    for (int jr = 0; jr < 4; jr++) {
      float mx = fmaxf(fmaxf(sc[0][jr], sc[1][jr]), fmaxf(sc[2][jr], sc[3][jr]));
#pragma unroll
      for (int d = 1; d < 16; d <<= 1) mx = fmaxf(mx, __shfl_xor(mx, d));
      mx8[jr] = mx;
      need |= (mx > mrow[jr] + 8.0f);
    }
    if (__any(need)) {  // rescale path: rare after the first tile
#pragma unroll
      for (int jr = 0; jr < 4; jr++) {
        const float mnew = fmaxf(mrow[jr], mx8[jr]);
        const float alpha = fast_exp2(mrow[jr] - mnew);  // first tile: exp2(-inf)=0
        mrow[jr] = mnew;
        lrow[jr] *= alpha;
#pragma unroll
        for (int jd = 0; jd < 4; jd++) o[jd][jr] *= alpha;
      }
    }
#pragma unroll
    for (int jr = 0; jr < 4; jr++) {
      const float m = mrow[jr];
      const float p0 = fast_exp2(sc[0][jr] - m), p1 = fast_exp2(sc[1][jr] - m);
      const float p2 = fast_exp2(sc[2][jr] - m), p3 = fast_exp2(sc[3][jr] - m);
      float rs = (p0 + p1) + (p2 + p3);
#pragma unroll
      for (int d = 1; d < 16; d <<= 1) rs += __shfl_xor(rs, d);
      lrow[jr] += rs;
      // write P (C-layout -> LDS, swizzled); wave-private region, no barrier needed
      const int prow = lhi * 4 + jr;   // 0..15
      char* pbase = (char*)Pl[wid] + prow * 128;
      const int swz = (prow & 7) << 4;
      *(ushort*)(pbase + ((0 * 32 + l15 * 2) ^ swz)) = f2bf_trunc(p0);
      *(ushort*)(pbase + ((1 * 32 + l15 * 2) ^ swz)) = f2bf_trunc(p1);
      *(ushort*)(pbase + ((2 * 32 + l15 * 2) ^ swz)) = f2bf_trunc(p2);
      *(ushort*)(pbase + ((3 * 32 + l15 * 2) ^ swz)) = f2bf_trunc(p3);
    }

    // PV: O[16 q][64 d] += P[16][64] @ V[64][64]
    bf16x8 ap[2], bvf[4][2];
    {
      const int row = l15;
      const int swz = (row & 7) << 4;
#pragma unroll
      for (int ks = 0; ks < 2; ks++)
        ap[ks] = *reinterpret_cast<const bf16x8*>(
            (const char*)Pl[wid] + row * 128 + ((ks * 64 + lhi * 16) ^ swz));
    }
#pragma unroll
    for (int jd = 0; jd < 4; jd++) {
      const int row = jd * 16 + l15;
      const int swz = (row & 7) << 4;
#pragma unroll
      for (int ks = 0; ks < 2; ks++)
        bvf[jd][ks] = *reinterpret_cast<const bf16x8*>(
            (const char*)Vt[cur] + row * 128 + ((ks * 64 + lhi * 16) ^ swz));
    }
#pragma unroll
    for (int jd = 0; jd < 4; jd++)
#pragma unroll
      for (int ks = 0; ks < 2; ks++)
        o[jd] = __builtin_amdgcn_mfma_f32_16x16x32_bf16(ap[ks], bvf[jd][ks], o[jd], 0, 0, 0);

    __syncthreads();  // single barrier/tile: drains vmcnt (next buf ready); all waves done with cur
  }

  // epilogue: ctx[b][q][h*64+d] = O / l
  const int b = bh >> 4, h = bh & 15;
  ushort* cb = ctx + (size_t)b * SEQ * DM + (size_t)h * HDIM;
#pragma unroll
  for (int jr = 0; jr < 4; jr++) {
    const float inv = 1.0f / lrow[jr];
    const int q = qw + lhi * 4 + jr;
#pragma unroll
    for (int jd = 0; jd < 4; jd++)
      cb[(size_t)q * DM + jd * 16 + l15] = f2bf(o[jd][jr] * inv);
  }
}

// ---------------- output projection: [4096,1024] @ [1024,1024]^T + bo, f32 out ----------------
__global__ __launch_bounds__(256) void gemm_out(
    const ushort* __restrict__ A,   // ctx bf16 [4096][1024]
    const ushort* __restrict__ Bw,  // wob [1024][1024]
    const float* __restrict__ bo, float* __restrict__ out)
{
  __shared__ ushort As[128 * 32];
  __shared__ ushort Bs[128 * 32];
  const int tid = threadIdx.x;
  const int lane = tid & 63, wid = tid >> 6;
  const int wr = wid >> 1, wc = wid & 1;
  const int l15 = lane & 15, lhi = lane >> 4;
  const int bm = blockIdx.x, bn = blockIdx.y;

  f32x4 acc[4][4] = {};

  const int strow = tid >> 2;
  const int stcol = (tid & 3) * 8;
  const ushort* Ag0 = A  + (size_t)(bm * 128 + strow) * 1024 + stcol;
  const ushort* Ag1 = Ag0 + 64 * 1024;
  const ushort* Bg0 = Bw + (size_t)(bn * 128 + strow) * 1024 + stcol;
  const ushort* Bg1 = Bg0 + 64 * 1024;
  ushort* Asl = As + tid * 8;
  ushort* Bsl = Bs + tid * 8;

  for (int k0 = 0; k0 < 1024; k0 += 32) {
    gll16(Ag0 + k0, Asl);
    gll16(Ag1 + k0, Asl + 2048);
    gll16(Bg0 + k0, Bsl);
    gll16(Bg1 + k0, Bsl + 2048);
    __syncthreads();
    bf16x8 af[4], bf[4];
#pragma unroll
    for (int i = 0; i < 4; i++)
      af[i] = *reinterpret_cast<const bf16x8*>(As + (wr * 64 + i * 16 + l15) * 32 + lhi * 8);
#pragma unroll
    for (int j = 0; j < 4; j++)
      bf[j] = *reinterpret_cast<const bf16x8*>(Bs + (wc * 64 + j * 16 + l15) * 32 + lhi * 8);
#pragma unroll
    for (int i = 0; i < 4; i++)
#pragma unroll
      for (int j = 0; j < 4; j++)
        acc[i][j] = __builtin_amdgcn_mfma_f32_16x16x32_bf16(af[i], bf[j], acc[i][j], 0, 0, 0);
    __syncthreads();
  }

  const int ncol0 = bn * 128 + wc * 64;
  const int mrow0 = bm * 128 + wr * 64;
#pragma unroll
  for (int i = 0; i < 4; i++)
#pragma unroll
    for (int j = 0; j < 4; j++) {
      const int n = ncol0 + j * 16 + l15;
      const float bias = bo[n];
#pragma unroll
      for (int jr = 0; jr < 4; jr++) {
        const int m = mrow0 + i * 16 + lhi * 4 + jr;
        out[(size_t)m * 1024 + n] = acc[i][j][jr] + bias;
      }
    }
}

extern "C" void kernel_launch(void* const* d_in, const int* in_sizes, int n_in,
                              void* d_out, int out_size, void* d_ws, size_t ws_size,
                              hipStream_t stream) {
  (void)in_sizes; (void)n_in; (void)out_size; (void)ws_size;
  const float* x  = (const float*)d_in[0];
  const float* Wq = (const float*)d_in[1];
  const float* bq = (const float*)d_in[2];
  const float* Wk = (const float*)d_in[3];
  const float* bk = (const float*)d_in[4];
  const float* Wv = (const float*)d_in[5];
  const float* bv = (const float*)d_in[6];
  const float* Wo = (const float*)d_in[7];
  const float* bo = (const float*)d_in[8];
  float* out = (float*)d_out;

  // workspace layout (bytes): 48 MB total
  char* ws = (char*)d_ws;
  ushort* xb   = (ushort*)(ws);               // 8 MB   [4096][1024] bf16
  ushort* wqkv = (ushort*)(ws + 8388608);     // 6 MB   [3072][1024]
  ushort* wob  = (ushort*)(ws + 14680064);    // 2 MB   [1024][1024]
  ushort* qhb  = (ushort*)(ws + 16777216);    // 8 MB   [b,h,s,hd]
  ushort* khb  = (ushort*)(ws + 25165824);    // 8 MB   [b,h,s,hd]
  ushort* vth  = (ushort*)(ws + 33554432);    // 8 MB   [b,h,hd,s]
  ushort* ctx  = (ushort*)(ws + 41943040);    // 8 MB   [b,s,d]

  cast_all<<<8192, 256, 0, stream>>>(x, Wq, Wk, Wv, Wo, xb, wqkv, wob);
  gemm_qkv<<<dim3(32, 24), 256, 0, stream>>>(xb, wqkv, bq, bk, bv, qhb, khb, vth);
  attn_kernel<<<dim3(16, 32), 512, 0, stream>>>(qhb, khb, vth, ctx);
  gemm_out<<<dim3(32, 8), 256, 0, stream>>>(ctx, wob, bo, out);
}

// Round 7
// 214.425 us; speedup vs baseline: 1.2796x; 1.1836x over previous
//
#include <hip/hip_runtime.h>
#include <hip/hip_bf16.h>

// MHA forward: B=2, S=2048, D=1024, H=16, HD=64. f32 in/out, bf16 MFMA internally.
constexpr int NH   = 16;
constexpr int SEQ  = 2048;
constexpr int DM   = 1024;
constexpr int HDIM = 64;

typedef __attribute__((ext_vector_type(4)))  float f32x4;
typedef __attribute__((ext_vector_type(16))) float f32x16;
typedef __attribute__((ext_vector_type(8)))  short bf16x8;

typedef __attribute__((address_space(3))) unsigned int lds_u32_t;
typedef const __attribute__((address_space(1))) unsigned int glb_u32_t;

__device__ __forceinline__ void gll16(const void* g, void* l) {
  __builtin_amdgcn_global_load_lds((glb_u32_t*)g, (lds_u32_t*)l, 16, 0, 0);
}

__device__ __forceinline__ ushort f2bf(float f) {
  union { float f; unsigned u; } v; v.f = f;
  unsigned u = v.u;
  return (ushort)((u + 0x7fffu + ((u >> 16) & 1u)) >> 16);  // RNE
}

__device__ __forceinline__ float fast_exp2(float x) {
#if __has_builtin(__builtin_amdgcn_exp2f)
  return __builtin_amdgcn_exp2f(x);
#else
  return __expf(x * 0.69314718056f);
#endif
}

// v_cvt_pk_bf16_f32: lo half <- cvt(a), hi half <- cvt(b), RNE
__device__ __forceinline__ unsigned cvtpk(float a, float b) {
  unsigned r;
  asm("v_cvt_pk_bf16_f32 %0, %1, %2" : "=v"(r) : "v"(a), "v"(b));
  return r;
}

// v_permlane32_swap_b32: vdst lanes 32-63 <-> vsrc lanes 0-31.
// HAZARD: only safe when a and b come from DISTINCT defs — identical SSA
// values may be register-coalesced into `v_permlane32_swap_b32 v5, v5`
// (in-place half swap, loses own value). For same-value partner exchange
// use __shfl_xor(x, 32) instead. Here: all callers pass distinct asm defs.
__device__ __forceinline__ void plswap(unsigned &a, unsigned &b) {
  asm("v_permlane32_swap_b32 %0, %1" : "+v"(a), "+v"(b));
}

// ---------------- single cast kernel: all 5 f32->bf16 tensors ----------------
__global__ void cast_all(const float* __restrict__ x,
                         const float* __restrict__ wq, const float* __restrict__ wk,
                         const float* __restrict__ wv, const float* __restrict__ wo,
                         ushort* __restrict__ xb, ushort* __restrict__ wqkv,
                         ushort* __restrict__ wob) {
  const int i = blockIdx.x * blockDim.x + threadIdx.x;  // float4 index, total 2097152
  const float* src; ushort* dst; int off;
  if (i < 1048576)      { src = x;  dst = xb;             off = i; }
  else if (i < 1310720) { src = wq; dst = wqkv;           off = i - 1048576; }
  else if (i < 1572864) { src = wk; dst = wqkv + 1048576; off = i - 1310720; }
  else if (i < 1835008) { src = wv; dst = wqkv + 2097152; off = i - 1572864; }
  else                  { src = wo; dst = wob;            off = i - 1835008; }
  const float4 v = reinterpret_cast<const float4*>(src)[off];
  ushort4 o;
  o.x = f2bf(v.x); o.y = f2bf(v.y); o.z = f2bf(v.z); o.w = f2bf(v.w);
  reinterpret_cast<ushort4*>(dst)[off] = o;
}

// ---------------- fused QKV GEMM: [4096,1024] @ [3072,1024]^T ----------------
__global__ __launch_bounds__(256) void gemm_qkv(
    const ushort* __restrict__ A, const ushort* __restrict__ Bw,
    const float* __restrict__ bq, const float* __restrict__ bk, const float* __restrict__ bv,
    ushort* __restrict__ qh, ushort* __restrict__ kh, ushort* __restrict__ vth)
{
  __shared__ ushort As[128 * 32];
  __shared__ ushort Bs[128 * 32];
  const int tid = threadIdx.x;
  const int lane = tid & 63, wid = tid >> 6;
  const int wr = wid >> 1, wc = wid & 1;
  const int l15 = lane & 15, lhi = lane >> 4;
  const int bm = blockIdx.x, bn = blockIdx.y;

  f32x4 acc[4][4] = {};

  const int strow = tid >> 2;
  const int stcol = (tid & 3) * 8;
  const ushort* Ag0 = A  + (size_t)(bm * 128 + strow) * 1024 + stcol;
  const ushort* Ag1 = Ag0 + 64 * 1024;
  const ushort* Bg0 = Bw + (size_t)(bn * 128 + strow) * 1024 + stcol;
  const ushort* Bg1 = Bg0 + 64 * 1024;
  ushort* Asl = As + tid * 8;
  ushort* Bsl = Bs + tid * 8;

  for (int k0 = 0; k0 < 1024; k0 += 32) {
    gll16(Ag0 + k0, Asl);
    gll16(Ag1 + k0, Asl + 2048);
    gll16(Bg0 + k0, Bsl);
    gll16(Bg1 + k0, Bsl + 2048);
    __syncthreads();
    bf16x8 af[4], bf[4];
#pragma unroll
    for (int i = 0; i < 4; i++)
      af[i] = *reinterpret_cast<const bf16x8*>(As + (wr * 64 + i * 16 + l15) * 32 + lhi * 8);
#pragma unroll
    for (int j = 0; j < 4; j++)
      bf[j] = *reinterpret_cast<const bf16x8*>(Bs + (wc * 64 + j * 16 + l15) * 32 + lhi * 8);
#pragma unroll
    for (int i = 0; i < 4; i++)
#pragma unroll
      for (int j = 0; j < 4; j++)
        acc[i][j] = __builtin_amdgcn_mfma_f32_16x16x32_bf16(af[i], bf[j], acc[i][j], 0, 0, 0);
    __syncthreads();
  }

  const int ncol0 = bn * 128 + wc * 64;
  const int mrow0 = bm * 128 + wr * 64;
  const int which = ncol0 >> 10;  // 0=q 1=k 2=v

  if (which == 2) {
#pragma unroll
    for (int i = 0; i < 4; i++) {
#pragma unroll
      for (int j = 0; j < 4; j++) {
        const int nn = (ncol0 + j * 16 + l15) & 1023;
        const int h = nn >> 6, hd = nn & 63;
        const float bias = bv[nn];
        const int m0 = mrow0 + i * 16 + lhi * 4;
        const int b = m0 >> 11, s = m0 & 2047;
        ushort4 pk;
        pk.x = f2bf(acc[i][j][0] + bias);
        pk.y = f2bf(acc[i][j][1] + bias);
        pk.z = f2bf(acc[i][j][2] + bias);
        pk.w = f2bf(acc[i][j][3] + bias);
        *reinterpret_cast<ushort4*>(
            &vth[((size_t)(b * NH + h) * HDIM + hd) * SEQ + s]) = pk;
      }
    }
  } else {
    const float scl = (which == 0) ? 0.18033688f : 1.0f;  // 0.125 * log2(e) baked into Q
    const float* __restrict__ bptr = (which == 0) ? bq : bk;
    ushort* __restrict__ dst = (which == 0) ? qh : kh;
#pragma unroll
    for (int i = 0; i < 4; i++) {
#pragma unroll
      for (int j = 0; j < 4; j++) {
        const int nn = (ncol0 + j * 16 + l15) & 1023;
        const int h = nn >> 6, hd = nn & 63;
        const float bias = bptr[nn];
#pragma unroll
        for (int jr = 0; jr < 4; jr++) {
          const int m = mrow0 + i * 16 + lhi * 4 + jr;
          const int b = m >> 11, s = m & 2047;
          dst[((size_t)(b * NH + h) * SEQ + s) * HDIM + hd] = f2bf((acc[i][j][jr] + bias) * scl);
        }
      }
    }
  }
}

// ---------------- flash attention: in-register softmax (m214/T12 structure) ----
// 8 waves x 32 q-rows = 256 q/block; grid (8, 32) = 256 blocks = 1/CU.
// Swapped QK^T via mfma_32x32x16(K, Q): C col=lane&31=q, row=crow(r,hi)=kv.
// Each lane owns one full q-row: softmax = in-reg tree + 1 cross-32 exchange.
// P -> PV A-fragments via 16 cvt_pk + 8 permlane32_swap (no P LDS).
__global__ __launch_bounds__(512, 2) void attn_kernel(
    const ushort* __restrict__ qh, const ushort* __restrict__ kh,
    const ushort* __restrict__ vth, ushort* __restrict__ ctx)
{
  __shared__ __align__(16) ushort Kt[2][64 * 64];   // [kv][d] swizzled, dbuf
  __shared__ __align__(16) ushort Vt[2][64 * 64];   // [d][kv] swizzled, dbuf
  __shared__ float linv_s[8][32];
  const int tid = threadIdx.x, lane = tid & 63, wid = tid >> 6;
  const int l31 = lane & 31, hi = lane >> 5;
  const int bh = blockIdx.y;            // b*16+h
  const int q0 = blockIdx.x * 256;
  const int qw = q0 + wid * 32;         // this wave's 32 q-rows
  const int rswz = (lane & 7) << 4;     // row-XOR swizzle (row&7 == lane&7 for l31 rows)
  const int hi16 = hi * 16;

  // Q fragments (B-operand): lane holds Q[qw + l31][st*16 + hi*8 + 0..7], pre-scaled
  bf16x8 qf[4];
  const ushort* qb = qh + (size_t)bh * SEQ * HDIM;
#pragma unroll
  for (int st = 0; st < 4; st++)
    qf[st] = *reinterpret_cast<const bf16x8*>(
        qb + (size_t)(qw + l31) * HDIM + st * 16 + hi * 8);

  f32x16 o0 = {}, o1 = {};              // O[d 0..31], O[d 32..63] for q=crow(r,hi)
  float mrow = -INFINITY, lrow = 0.f;   // per-lane scalars: lane owns q = l31

  const int srow = tid >> 3;            // 512 thr: rows 0..63, one gll16 per 8KB tile
  const int scole = (((tid & 7) * 16) ^ ((srow & 7) << 4)) >> 1;
  const ushort* kbase = kh + (size_t)bh * SEQ * HDIM;
  const ushort* vbase = vth + (size_t)bh * HDIM * SEQ;

  auto stage = [&](int buf, int kv0) {
    gll16(kbase + (size_t)(kv0 + srow) * HDIM + scole, &Kt[buf][tid * 8]);
    gll16(vbase + (size_t)srow * SEQ + kv0 + scole, &Vt[buf][tid * 8]);
  };

  stage(0, 0);
  __syncthreads();

  for (int t = 0; t < SEQ / 64; ++t) {
    const int cur = t & 1;
    if (t < SEQ / 64 - 1) stage(cur ^ 1, (t + 1) * 64);  // issue-early prefetch

    // ---- QK^T (swapped): acc0 = kv 0..31, acc1 = kv 32..63, col = q = l31 ----
    const char* kb = (const char*)Kt[cur];
    bf16x8 kf0[4], kf1[4];
#pragma unroll
    for (int st = 0; st < 4; st++) {
      kf0[st] = *reinterpret_cast<const bf16x8*>(kb + l31 * 128 + ((st * 32 + hi16) ^ rswz));
      kf1[st] = *reinterpret_cast<const bf16x8*>(kb + (32 + l31) * 128 + ((st * 32 + hi16) ^ rswz));
    }
    f32x16 acc0 = {}, acc1 = {};
    __builtin_amdgcn_s_setprio(1);
#pragma unroll
    for (int st = 0; st < 4; st++) {
      acc0 = __builtin_amdgcn_mfma_f32_32x32x16_bf16(kf0[st], qf[st], acc0, 0, 0, 0);
      acc1 = __builtin_amdgcn_mfma_f32_32x32x16_bf16(kf1[st], qf[st], acc1, 0, 0, 0);
    }
    __builtin_amdgcn_s_setprio(0);

    // ---- in-register online softmax (exp2-domain, defer-rescale THR=8) ----
    float tm[8];
#pragma unroll
    for (int r = 0; r < 8; r++)
      tm[r] = fmaxf(fmaxf(acc0[r], acc0[r + 8]), fmaxf(acc1[r], acc1[r + 8]));
    float mx = fmaxf(fmaxf(fmaxf(tm[0], tm[1]), fmaxf(tm[2], tm[3])),
                     fmaxf(fmaxf(tm[4], tm[5]), fmaxf(tm[6], tm[7])));
    mx = fmaxf(mx, __shfl_xor(mx, 32));   // partner-lane exchange (NOT plswap: same-def hazard)
    if (__any(mx > mrow + 8.0f)) {
      const float mnew = fmaxf(mrow, mx);
      const float alpha = fast_exp2(mrow - mnew);  // first tile: exp2(-inf)=0
      mrow = mnew;
      lrow *= alpha;
      o0 *= alpha; o1 *= alpha;
    }
    float p0[16], p1[16];
#pragma unroll
    for (int r = 0; r < 16; r++) {
      p0[r] = fast_exp2(acc0[r] - mrow);
      p1[r] = fast_exp2(acc1[r] - mrow);
    }
    float ss[8];
#pragma unroll
    for (int r = 0; r < 8; r++) ss[r] = (p0[r] + p0[r + 8]) + (p1[r] + p1[r + 8]);
    float rs = ((ss[0] + ss[1]) + (ss[2] + ss[3])) + ((ss[4] + ss[5]) + (ss[6] + ss[7]));
    rs += __shfl_xor(rs, 32);             // partner-lane exchange (NOT plswap: same-def hazard)
    lrow += rs;

    // ---- P -> bf16 PV A-fragments: 16 cvt_pk + 8 permlane32_swap ----
    // pa[st] elem j = P[q=l31][kv = st*16 + hi*8 + j]
    union PU { unsigned u[4]; bf16x8 v; };
    PU pa[4];
    {
      unsigned a0 = cvtpk(p0[0], p0[1]),   b0 = cvtpk(p0[4], p0[5]);   plswap(a0, b0);
      unsigned a1 = cvtpk(p0[2], p0[3]),   b1 = cvtpk(p0[6], p0[7]);   plswap(a1, b1);
      unsigned a2 = cvtpk(p0[8], p0[9]),   b2 = cvtpk(p0[12], p0[13]); plswap(a2, b2);
      unsigned a3 = cvtpk(p0[10], p0[11]), b3 = cvtpk(p0[14], p0[15]); plswap(a3, b3);
      pa[0].u[0] = a0; pa[0].u[1] = a1; pa[0].u[2] = b0; pa[0].u[3] = b1;
      pa[1].u[0] = a2; pa[1].u[1] = a3; pa[1].u[2] = b2; pa[1].u[3] = b3;
      unsigned c0 = cvtpk(p1[0], p1[1]),   d0 = cvtpk(p1[4], p1[5]);   plswap(c0, d0);
      unsigned c1 = cvtpk(p1[2], p1[3]),   d1 = cvtpk(p1[6], p1[7]);   plswap(c1, d1);
      unsigned c2 = cvtpk(p1[8], p1[9]),   d2 = cvtpk(p1[12], p1[13]); plswap(c2, d2);
      unsigned c3 = cvtpk(p1[10], p1[11]), d3 = cvtpk(p1[14], p1[15]); plswap(c3, d3);
      pa[2].u[0] = c0; pa[2].u[1] = c1; pa[2].u[2] = d0; pa[2].u[3] = d1;
      pa[3].u[0] = c2; pa[3].u[1] = c3; pa[3].u[2] = d2; pa[3].u[3] = d3;
    }

    // ---- PV: O[q][d] += P @ V, B-frag from Vt[d][kv] ----
    const char* vb = (const char*)Vt[cur];
    bf16x8 bv0[4], bv1[4];
#pragma unroll
    for (int st = 0; st < 4; st++) {
      bv0[st] = *reinterpret_cast<const bf16x8*>(vb + l31 * 128 + ((st * 32 + hi16) ^ rswz));
      bv1[st] = *reinterpret_cast<const bf16x8*>(vb + (32 + l31) * 128 + ((st * 32 + hi16) ^ rswz));
    }
    __builtin_amdgcn_s_setprio(1);
#pragma unroll
    for (int st = 0; st < 4; st++) {
      o0 = __builtin_amdgcn_mfma_f32_32x32x16_bf16(pa[st].v, bv0[st], o0, 0, 0, 0);
      o1 = __builtin_amdgcn_mfma_f32_32x32x16_bf16(pa[st].v, bv1[st], o1, 0, 0, 0);
    }
    __builtin_amdgcn_s_setprio(0);

    __syncthreads();  // drains vmcnt (next buf ready); all waves done with cur
  }

  // ---- epilogue: ctx[b][q][h*64+d] = O[q][d] / l[q] ----
  const int b = bh >> 4, h = bh & 15;
  linv_s[wid][l31] = 1.0f / lrow;  // lane owns q=l31 (dup write from hi half benign)
  ushort* cb = ctx + (size_t)b * SEQ * DM + (size_t)h * HDIM;
#pragma unroll
  for (int r = 0; r < 16; r++) {
    const int qrow = (r & 3) + 8 * (r >> 2) + 4 * hi;  // crow(r,hi)
    const float iv = linv_s[wid][qrow];
    ushort* rp = cb + (size_t)(qw + qrow) * DM;
    rp[l31]      = f2bf(o0[r] * iv);
    rp[32 + l31] = f2bf(o1[r] * iv);
  }
}

// ---------------- output projection: [4096,1024] @ [1024,1024]^T + bo, f32 out ----------------
__global__ __launch_bounds__(256) void gemm_out(
    const ushort* __restrict__ A, const ushort* __restrict__ Bw,
    const float* __restrict__ bo, float* __restrict__ out)
{
  __shared__ ushort As[128 * 32];
  __shared__ ushort Bs[128 * 32];
  const int tid = threadIdx.x;
  const int lane = tid & 63, wid = tid >> 6;
  const int wr = wid >> 1, wc = wid & 1;
  const int l15 = lane & 15, lhi = lane >> 4;
  const int bm = blockIdx.x, bn = blockIdx.y;

  f32x4 acc[4][4] = {};

  const int strow = tid >> 2;
  const int stcol = (tid & 3) * 8;
  const ushort* Ag0 = A  + (size_t)(bm * 128 + strow) * 1024 + stcol;
  const ushort* Ag1 = Ag0 + 64 * 1024;
  const ushort* Bg0 = Bw + (size_t)(bn * 128 + strow) * 1024 + stcol;
  const ushort* Bg1 = Bg0 + 64 * 1024;
  ushort* Asl = As + tid * 8;
  ushort* Bsl = Bs + tid * 8;

  for (int k0 = 0; k0 < 1024; k0 += 32) {
    gll16(Ag0 + k0, Asl);
    gll16(Ag1 + k0, Asl + 2048);
    gll16(Bg0 + k0, Bsl);
    gll16(Bg1 + k0, Bsl + 2048);
    __syncthreads();
    bf16x8 af[4], bf[4];
#pragma unroll
    for (int i = 0; i < 4; i++)
      af[i] = *reinterpret_cast<const bf16x8*>(As + (wr * 64 + i * 16 + l15) * 32 + lhi * 8);
#pragma unroll
    for (int j = 0; j < 4; j++)
      bf[j] = *reinterpret_cast<const bf16x8*>(Bs + (wc * 64 + j * 16 + l15) * 32 + lhi * 8);
#pragma unroll
    for (int i = 0; i < 4; i++)
#pragma unroll
      for (int j = 0; j < 4; j++)
        acc[i][j] = __builtin_amdgcn_mfma_f32_16x16x32_bf16(af[i], bf[j], acc[i][j], 0, 0, 0);
    __syncthreads();
  }

  const int ncol0 = bn * 128 + wc * 64;
  const int mrow0 = bm * 128 + wr * 64;
#pragma unroll
  for (int i = 0; i < 4; i++)
#pragma unroll
    for (int j = 0; j < 4; j++) {
      const int n = ncol0 + j * 16 + l15;
      const float bias = bo[n];
#pragma unroll
      for (int jr = 0; jr < 4; jr++) {
        const int m = mrow0 + i * 16 + lhi * 4 + jr;
        out[(size_t)m * 1024 + n] = acc[i][j][jr] + bias;
      }
    }
}

extern "C" void kernel_launch(void* const* d_in, const int* in_sizes, int n_in,
                              void* d_out, int out_size, void* d_ws, size_t ws_size,
                              hipStream_t stream) {
  (void)in_sizes; (void)n_in; (void)out_size; (void)ws_size;
  const float* x  = (const float*)d_in[0];
  const float* Wq = (const float*)d_in[1];
  const float* bq = (const float*)d_in[2];
  const float* Wk = (const float*)d_in[3];
  const float* bk = (const float*)d_in[4];
  const float* Wv = (const float*)d_in[5];
  const float* bv = (const float*)d_in[6];
  const float* Wo = (const float*)d_in[7];
  const float* bo = (const float*)d_in[8];
  float* out = (float*)d_out;

  char* ws = (char*)d_ws;
  ushort* xb   = (ushort*)(ws);               // 8 MB   [4096][1024] bf16
  ushort* wqkv = (ushort*)(ws + 8388608);     // 6 MB   [3072][1024]
  ushort* wob  = (ushort*)(ws + 14680064);    // 2 MB   [1024][1024]
  ushort* qhb  = (ushort*)(ws + 16777216);    // 8 MB   [b,h,s,hd]
  ushort* khb  = (ushort*)(ws + 25165824);    // 8 MB   [b,h,s,hd]
  ushort* vth  = (ushort*)(ws + 33554432);    // 8 MB   [b,h,hd,s]
  ushort* ctx  = (ushort*)(ws + 41943040);    // 8 MB   [b,s,d]

  cast_all<<<8192, 256, 0, stream>>>(x, Wq, Wk, Wv, Wo, xb, wqkv, wob);
  gemm_qkv<<<dim3(32, 24), 256, 0, stream>>>(xb, wqkv, bq, bk, bv, qhb, khb, vth);
  attn_kernel<<<dim3(8, 32), 512, 0, stream>>>(qhb, khb, vth, ctx);
  gemm_out<<<dim3(32, 8), 256, 0, stream>>>(ctx, wob, bo, out);
}